// Round 18
// baseline (490.347 us; speedup 1.0000x reference)
//
#include <hip/hip_runtime.h>

// ---------------------------------------------------------------------------
// GIN 3-layer forward (R18): R17 + degree-sorted node permutation for agg.
//   scan1: + degree histogram (256 bins, clamp 255)
//   dscan: 1-block exclusive scan of degree bins -> dcur
//   scan3: + counting-sort scatter perm[pos]=node (order within bin arbitrary;
//          per-node arithmetic unchanged -> deterministic output)
//   agg:   block processes perm[...] -> all nodes in a block have ~equal
//          degree -> no intra-block degree stragglers.
//   Everything else = R17 (proven): prep, binA/binB u16 adj, sliced agg, gemm.
// ---------------------------------------------------------------------------

typedef __attribute__((ext_vector_type(8))) short short8;
typedef __attribute__((ext_vector_type(4))) float f32x4;

#define NBUK   256
#define BNODES 196   // ceil(50000/256)

__device__ inline unsigned short f2bf(float f) {
    union { float f; unsigned u; } v; v.f = f;
    unsigned r = v.u + 0x7fffu + ((v.u >> 16) & 1u);   // RNE
    return (unsigned short)(r >> 16);
}
__device__ inline float bflo(unsigned u) { return __uint_as_float(u << 16); }
__device__ inline float bfhi(unsigned u) { return __uint_as_float(u & 0xffff0000u); }

__device__ __forceinline__ void gload_lds16(const unsigned short* g, unsigned short* l) {
    __builtin_amdgcn_global_load_lds(
        (const __attribute__((address_space(1))) unsigned int*)g,
        (__attribute__((address_space(3))) unsigned int*)l,
        16, 0, 0);
}

#define ACC8(v) { acc[0]+=bflo(v.x); acc[1]+=bfhi(v.x); acc[2]+=bflo(v.y); acc[3]+=bfhi(v.y); \
                  acc[4]+=bflo(v.z); acc[5]+=bfhi(v.z); acc[6]+=bflo(v.w); acc[7]+=bfhi(v.w); }

// ---------------- prep: x -> sliced bf16 [4][M][32], hist, W subtiled ------
__global__ __launch_bounds__(256) void prep_kernel(
    const float* __restrict__ x, const int* __restrict__ dst,
    const float* __restrict__ W1, const float* __restrict__ W2,
    const float* __restrict__ W3,
    unsigned short* __restrict__ xb, int* __restrict__ cnt,
    unsigned short* __restrict__ Ws1, unsigned short* __restrict__ Ws2,
    unsigned short* __restrict__ Ws3, int M, int nE)
{
    const int i  = blockIdx.x * 256 + threadIdx.x;
    const int nx = M * 16;
    if (i < nx) {
        const float4* xf = reinterpret_cast<const float4*>(x);
        float4 a = xf[2*i], b = xf[2*i + 1];
        uint4 o;
        o.x = (unsigned)f2bf(a.x) | ((unsigned)f2bf(a.y) << 16);
        o.y = (unsigned)f2bf(a.z) | ((unsigned)f2bf(a.w) << 16);
        o.z = (unsigned)f2bf(b.x) | ((unsigned)f2bf(b.y) << 16);
        o.w = (unsigned)f2bf(b.z) | ((unsigned)f2bf(b.w) << 16);
        const int node  = i >> 4;
        const int chunk = i & 15;
        const int cs    = chunk >> 2;        // 32-ch slice 0..3
        const size_t idx = ((size_t)cs * M + node) * 32 + (chunk & 3) * 8;
        *reinterpret_cast<uint4*>(xb + idx) = o;
    } else if (i < nx + nE) {
        atomicAdd(&cnt[dst[i - nx]], 1);
    } else {
        int j = i - nx - nE;
        const float* W; unsigned short* D;
        if (j < 32768)       { W = W1; D = Ws1; }
        else if (j < 98304)  { W = W2; D = Ws2; j -= 32768; }
        else if (j < 163840) { W = W3; D = Ws3; j -= 98304; }
        else return;
        const int k = j >> 8, n = j & 255;
        D[((size_t)(k >> 3) * 256 + n) * 8 + (k & 7)] = f2bf(W[(size_t)k * 256 + n]);
    }
}

// ---------------- CSR scan (+ degree histogram) ----------------

__global__ __launch_bounds__(1024) void scan1_kernel(
    const int* __restrict__ cnt, int* __restrict__ excl,
    int* __restrict__ bsum, int* __restrict__ dhist, int n)
{
    __shared__ int sh[1024];
    const int tid = threadIdx.x;
    const int i = blockIdx.x * 1024 + tid;
    int v = (i < n) ? cnt[i] : 0;
    if (i < n) atomicAdd(&dhist[v > 255 ? 255 : v], 1);
    sh[tid] = v;
    __syncthreads();
    #pragma unroll
    for (int off = 1; off < 1024; off <<= 1) {
        int t = (tid >= off) ? sh[tid - off] : 0;
        __syncthreads();
        sh[tid] += t;
        __syncthreads();
    }
    if (i < n) excl[i] = sh[tid] - v;
    if (tid == 1023) bsum[blockIdx.x] = sh[1023];
}

// 1-block exclusive scan of degree histogram -> dcur
__global__ __launch_bounds__(256) void dscan_kernel(
    const int* __restrict__ dhist, int* __restrict__ dcur)
{
    __shared__ int sh[256];
    const int t = threadIdx.x;
    int v = dhist[t];
    sh[t] = v;
    __syncthreads();
    #pragma unroll
    for (int off = 1; off < 256; off <<= 1) {
        int u = (t >= off) ? sh[t - off] : 0;
        __syncthreads();
        sh[t] += u;
        __syncthreads();
    }
    dcur[t] = sh[t] - v;   // exclusive
}

// scan3: finalize row_start, init bucket cursors, counting-sort perm.
__global__ __launch_bounds__(1024) void scan3_kernel(
    const int* __restrict__ excl, const int* __restrict__ bsum,
    const int* __restrict__ cnt, int* __restrict__ dcur,
    int* __restrict__ perm,
    int* __restrict__ row_start, int* __restrict__ gcur,
    int n, int nE, int nbl)
{
    __shared__ int sb[64];
    const int tid = threadIdx.x;
    if (tid < 64) sb[tid] = (tid < nbl) ? bsum[tid] : 0;
    __syncthreads();
    #pragma unroll
    for (int off = 1; off < 64; off <<= 1) {
        int v = 0;
        if (tid < 64 && tid >= off) v = sb[tid - off];
        __syncthreads();
        if (tid < 64) sb[tid] += v;
        __syncthreads();
    }
    const int boff = sb[blockIdx.x] - bsum[blockIdx.x];
    const int i = blockIdx.x * 1024 + tid;
    if (i < n) {
        int v = excl[i] + boff;
        row_start[i] = v;
        if ((i % BNODES) == 0) gcur[i / BNODES] = v;
        int d = cnt[i]; if (d > 255) d = 255;
        const int pos = atomicAdd(&dcur[d], 1);
        perm[pos] = i;
    }
    if (i == 0) row_start[n] = nE;
}

// ---------------- binned CSR scatter ----------------

__global__ __launch_bounds__(256) void binA_kernel(
    const int* __restrict__ src, const int* __restrict__ dst,
    int* __restrict__ gcur, unsigned* __restrict__ pair_buf, int nE)
{
    __shared__ int lhist[NBUK];
    __shared__ int lbase[NBUK];
    const int t = threadIdx.x;
    lhist[t] = 0;
    __syncthreads();

    const int e0 = blockIdx.x * 4096;
    int d[16], s[16], r[16];
    #pragma unroll
    for (int i = 0; i < 16; ++i) {
        const int e = e0 + i * 256 + t;
        if (e < nE) {
            d[i] = dst[e];
            s[i] = src[e];
            r[i] = atomicAdd(&lhist[d[i] / BNODES], 1);
        }
    }
    __syncthreads();
    lbase[t] = lhist[t] ? atomicAdd(&gcur[t], lhist[t]) : 0;
    __syncthreads();
    #pragma unroll
    for (int i = 0; i < 16; ++i) {
        const int e = e0 + i * 256 + t;
        if (e < nE)
            pair_buf[lbase[d[i] / BNODES] + r[i]] =
                ((unsigned)d[i] << 16) | (unsigned)s[i];
    }
}

__global__ __launch_bounds__(256) void binB_kernel(
    const unsigned* __restrict__ pair_buf, const int* __restrict__ row_start,
    unsigned short* __restrict__ adj, int M)
{
    __shared__ int lcur[BNODES];
    const int b   = blockIdx.x;
    const int nb0 = b * BNODES;
    const int nb1 = min(nb0 + BNODES, M);
    const int nn  = nb1 - nb0;
    const int t   = threadIdx.x;
    if (nn <= 0) return;
    for (int i = t; i < nn; i += 256) lcur[i] = row_start[nb0 + i];
    __syncthreads();
    const int p0 = row_start[nb0];
    const int p1 = row_start[nb1];
    for (int p = p0 + t; p < p1; p += 256) {
        const unsigned pr = pair_buf[p];
        const int dn = (int)(pr >> 16);
        const int pos = atomicAdd(&lcur[dn - nb0], 1);
        adj[pos] = (unsigned short)(pr & 0xFFFFu);
    }
}

// ---------------- sliced aggregation, degree-sorted ----------------
// Block processes nodes perm[grp*64 .. grp*64+63] -> equal-degree threads.

template <int CIN, int NSLICE>
__global__ __launch_bounds__(256) void agg_sliced(
    const unsigned short* __restrict__ Xcs,
    const int* __restrict__ row_start, const unsigned short* __restrict__ adj,
    const int* __restrict__ perm,
    const float* __restrict__ eps_arr, int layer,
    unsigned short* __restrict__ H, int M)
{
    constexpr int SHIFT = (NSLICE == 8) ? 3 : 2;

    const int cs   = blockIdx.x & (NSLICE - 1);
    const int grp  = blockIdx.x >> SHIFT;
    const int nidx = grp * 64 + (threadIdx.x >> 2);
    const int c8   = threadIdx.x & 3;
    if (nidx >= M) return;
    const int node = perm[nidx];

    const uint4* __restrict__ X4 =
        reinterpret_cast<const uint4*>(Xcs) + (size_t)cs * M * 4;

    float acc[8] = {};
    const int s0 = row_start[node];
    const int s1 = row_start[node + 1];
    const int deg = s1 - s0;

    int j = s0;
    if (deg >= 4) {
        const int jend = s0 + (deg & ~3);
        int a0 = adj[j], a1 = adj[j+1], a2 = adj[j+2], a3 = adj[j+3];
        uint4 p0 = X4[(size_t)a0 * 4 + c8];
        uint4 p1 = X4[(size_t)a1 * 4 + c8];
        uint4 p2 = X4[(size_t)a2 * 4 + c8];
        uint4 p3 = X4[(size_t)a3 * 4 + c8];
        for (j += 4; j < jend; j += 4) {
            const int b0 = adj[j], b1 = adj[j+1], b2 = adj[j+2], b3 = adj[j+3];
            const uint4 n0 = X4[(size_t)b0 * 4 + c8];
            const uint4 n1 = X4[(size_t)b1 * 4 + c8];
            const uint4 n2 = X4[(size_t)b2 * 4 + c8];
            const uint4 n3 = X4[(size_t)b3 * 4 + c8];
            ACC8(p0); ACC8(p1); ACC8(p2); ACC8(p3);
            p0 = n0; p1 = n1; p2 = n2; p3 = n3;
        }
        ACC8(p0); ACC8(p1); ACC8(p2); ACC8(p3);
    }
    for (; j < s1; ++j) {
        const uint4 v = X4[(size_t)adj[j] * 4 + c8];
        ACC8(v);
    }

    const uint4 xv = X4[(size_t)node * 4 + c8];
    const float epsv = 1.0f + eps_arr[layer];
    float o[8];
    o[0] = epsv * bflo(xv.x) + acc[0]; o[1] = epsv * bfhi(xv.x) + acc[1];
    o[2] = epsv * bflo(xv.y) + acc[2]; o[3] = epsv * bfhi(xv.y) + acc[3];
    o[4] = epsv * bflo(xv.z) + acc[4]; o[5] = epsv * bfhi(xv.z) + acc[5];
    o[6] = epsv * bflo(xv.w) + acc[6]; o[7] = epsv * bfhi(xv.w) + acc[7];

    uint4 ov;
    ov.x = (unsigned)f2bf(o[0]) | ((unsigned)f2bf(o[1]) << 16);
    ov.y = (unsigned)f2bf(o[2]) | ((unsigned)f2bf(o[3]) << 16);
    ov.z = (unsigned)f2bf(o[4]) | ((unsigned)f2bf(o[5]) << 16);
    ov.w = (unsigned)f2bf(o[6]) | ((unsigned)f2bf(o[7]) << 16);
    *reinterpret_cast<uint4*>(H + (size_t)node * CIN + cs * 32 + c8 * 8) = ov;
}

// ---------------- GEMM (R15/R16, unchanged) ----------------
template <int CIN, int RELU, int OUTMODE>
__global__ __launch_bounds__(256) void gemm_tiled(
    const unsigned short* __restrict__ H, const unsigned short* __restrict__ Wsub,
    const float* __restrict__ bias, void* __restrict__ out, int M)
{
    constexpr int S = CIN / 32;

    __shared__ __align__(16) unsigned short As[2][4][64][8];

    const int t    = threadIdx.x;
    const int bm   = blockIdx.x * 64;
    const int w    = t >> 6, lane = t & 63;
    const int lr   = lane & 15, ko = lane >> 4;

    const int srow = t & 63;
    const int skb  = t >> 6;
    const unsigned short* aG = H + (size_t)(bm + srow) * CIN + skb * 8;

    f32x4 acc[4][4];
    #pragma unroll
    for (int fn = 0; fn < 4; ++fn) {
        const float bb = bias[w*64 + fn*16 + lr];
        #pragma unroll
        for (int fm = 0; fm < 4; ++fm) {
            acc[fm][fn][0] = bb; acc[fm][fn][1] = bb;
            acc[fm][fn][2] = bb; acc[fm][fn][3] = bb;
        }
    }

    gload_lds16(aG, &As[0][skb][srow][0]);

    int cur = 0;
    for (int s = 0; s < S; ++s) {
        __syncthreads();
        if (s + 1 < S)
            gload_lds16(aG + (s+1)*32, &As[cur ^ 1][skb][srow][0]);

        short8 af[4], bf8[4];
        #pragma unroll
        for (int fm = 0; fm < 4; ++fm)
            af[fm] = *reinterpret_cast<const short8*>(&As[cur][ko][fm*16 + lr][0]);
        #pragma unroll
        for (int fn = 0; fn < 4; ++fn)
            bf8[fn] = *reinterpret_cast<const short8*>(
                Wsub + ((size_t)(s*4 + ko) * 256 + w*64 + fn*16 + lr) * 8);
        #pragma unroll
        for (int fm = 0; fm < 4; ++fm)
            #pragma unroll
            for (int fn = 0; fn < 4; ++fn)
                acc[fm][fn] = __builtin_amdgcn_mfma_f32_16x16x32_bf16(
                    af[fm], bf8[fn], acc[fm][fn], 0, 0, 0);

        cur ^= 1;
    }

    #pragma unroll
    for (int fm = 0; fm < 4; ++fm) {
        #pragma unroll
        for (int fn = 0; fn < 4; ++fn) {
            const int col = w*64 + fn*16 + lr;
            #pragma unroll
            for (int r = 0; r < 4; ++r) {
                const int row = bm + fm*16 + ko*4 + r;
                if (row < M) {
                    float v = acc[fm][fn][r];
                    if (RELU) v = fmaxf(v, 0.f);
                    if (OUTMODE == 1) {
                        ((unsigned short*)out)[(size_t)(col >> 5) * M * 32
                                               + (size_t)row * 32 + (col & 31)] = f2bf(v);
                    } else {
                        ((float*)out)[(size_t)row * 256 + col] = v;
                    }
                }
            }
        }
    }
}

// ---------------- launch ----------------

extern "C" void kernel_launch(void* const* d_in, const int* in_sizes, int n_in,
                              void* d_out, int out_size, void* d_ws, size_t ws_size,
                              hipStream_t stream)
{
    const float* x   = (const float*)d_in[0];
    const int*   ei  = (const int*)  d_in[1];
    const float* W1  = (const float*)d_in[2];
    const float* b1  = (const float*)d_in[3];
    const float* W2  = (const float*)d_in[4];
    const float* b2  = (const float*)d_in[5];
    const float* W3  = (const float*)d_in[6];
    const float* b3  = (const float*)d_in[7];
    const float* eps = (const float*)d_in[8];

    const int M  = in_sizes[0] / 128;   // 50000
    const int nE = in_sizes[1] / 2;     // 800000
    const int Mp = ((M + 63) / 64) * 64;
    const int* srcI = ei;
    const int* dstI = ei + nE;

    // workspace layout
    char* p = (char*)d_ws;
    unsigned short* xb_cs = (unsigned short*)p; p += (size_t)M  * 128 * 2;  // [4][M][32]
    unsigned short* Arow  = (unsigned short*)p; p += (size_t)Mp * 256 * 2;  // row-major A
    unsigned short* s_cs  = (unsigned short*)p; p += (size_t)M  * 256 * 2;  // [8][M][32]
    unsigned short* Ws1   = (unsigned short*)p; p += (size_t)128 * 256 * 2;
    unsigned short* Ws2   = (unsigned short*)p; p += (size_t)256 * 256 * 2;
    unsigned short* Ws3   = (unsigned short*)p; p += (size_t)256 * 256 * 2;
    int* cnt       = (int*)p; p += (size_t)M * 4;
    int* dhist     = (int*)p; p += 256 * 4;       // memset with cnt
    int* dcur      = (int*)p; p += 256 * 4;
    int* perm      = (int*)p; p += (size_t)M * 4;
    int* excl      = (int*)p; p += (size_t)M * 4;
    int* bsum      = (int*)p; p += 64 * 4;
    int* gcur      = (int*)p; p += NBUK * 4;
    int* row_start = (int*)p; p += (size_t)(M + 2) * 4;
    unsigned* pair_buf = (unsigned*)p; p += (size_t)nE * 4;
    unsigned short* adj = (unsigned short*)p; p += (size_t)nE * 2;

    const int nbl = (M + 1023) / 1024;   // 49

    hipMemsetAsync(cnt, 0, ((size_t)M + 256) * sizeof(int), stream);   // cnt + dhist
    {
        const int total = M * 16 + nE + 163840;
        prep_kernel<<<(total + 255) / 256, 256, 0, stream>>>(
            x, dstI, W1, W2, W3, xb_cs, cnt, Ws1, Ws2, Ws3, M, nE);
    }
    scan1_kernel<<<nbl, 1024, 0, stream>>>(cnt, excl, bsum, dhist, M);
    dscan_kernel<<<1, 256, 0, stream>>>(dhist, dcur);
    scan3_kernel<<<nbl, 1024, 0, stream>>>(excl, bsum, cnt, dcur, perm,
                                           row_start, gcur, M, nE, nbl);
    binA_kernel<<<(nE + 4095) / 4096, 256, 0, stream>>>(srcI, dstI, gcur, pair_buf, nE);
    binB_kernel<<<NBUK, 256, 0, stream>>>(pair_buf, row_start, adj, M);

    const int ablk1 = 4 * ((M + 63) / 64);   // layer 1: 4 slices
    const int ablk2 = 8 * ((M + 63) / 64);   // layers 2/3: 8 slices
    const int gblk  = Mp / 64;               // 782

    // layer 1 (CIN=128): xb_cs -> Arow -> s_cs
    agg_sliced<128, 4><<<ablk1, 256, 0, stream>>>(xb_cs, row_start, adj, perm, eps, 0, Arow, M);
    gemm_tiled<128, 1, 1><<<gblk, 256, 0, stream>>>(Arow, Ws1, b1, s_cs, M);

    // layer 2 (CIN=256): s_cs -> Arow -> s_cs
    agg_sliced<256, 8><<<ablk2, 256, 0, stream>>>(s_cs, row_start, adj, perm, eps, 1, Arow, M);
    gemm_tiled<256, 1, 1><<<gblk, 256, 0, stream>>>(Arow, Ws2, b2, s_cs, M);

    // layer 3 (CIN=256): s_cs -> Arow -> d_out (fp32 row-major)
    agg_sliced<256, 8><<<ablk2, 256, 0, stream>>>(s_cs, row_start, adj, perm, eps, 2, Arow, M);
    gemm_tiled<256, 0, 0><<<gblk, 256, 0, stream>>>(Arow, Ws3, b3, d_out, M);
}

// Round 19
// 276.468 us; speedup vs baseline: 1.7736x; 1.7736x over previous
//
#include <hip/hip_runtime.h>

// ---------------------------------------------------------------------------
// GIN 3-layer forward (R19): R18 with the scan3 atomic contention fixed.
//   scan3 counting-sort now uses per-block LDS histogram + rank and ONE
//   global atomic per (block,bin) reservation (binA pattern) instead of
//   50k contended atomics on ~30 hot degree bins.
//   Everything else = R18/R17 (proven).
// ---------------------------------------------------------------------------

typedef __attribute__((ext_vector_type(8))) short short8;
typedef __attribute__((ext_vector_type(4))) float f32x4;

#define NBUK   256
#define BNODES 196   // ceil(50000/256)

__device__ inline unsigned short f2bf(float f) {
    union { float f; unsigned u; } v; v.f = f;
    unsigned r = v.u + 0x7fffu + ((v.u >> 16) & 1u);   // RNE
    return (unsigned short)(r >> 16);
}
__device__ inline float bflo(unsigned u) { return __uint_as_float(u << 16); }
__device__ inline float bfhi(unsigned u) { return __uint_as_float(u & 0xffff0000u); }

__device__ __forceinline__ void gload_lds16(const unsigned short* g, unsigned short* l) {
    __builtin_amdgcn_global_load_lds(
        (const __attribute__((address_space(1))) unsigned int*)g,
        (__attribute__((address_space(3))) unsigned int*)l,
        16, 0, 0);
}

#define ACC8(v) { acc[0]+=bflo(v.x); acc[1]+=bfhi(v.x); acc[2]+=bflo(v.y); acc[3]+=bfhi(v.y); \
                  acc[4]+=bflo(v.z); acc[5]+=bfhi(v.z); acc[6]+=bflo(v.w); acc[7]+=bfhi(v.w); }

// ---------------- prep ----------------
__global__ __launch_bounds__(256) void prep_kernel(
    const float* __restrict__ x, const int* __restrict__ dst,
    const float* __restrict__ W1, const float* __restrict__ W2,
    const float* __restrict__ W3,
    unsigned short* __restrict__ xb, int* __restrict__ cnt,
    unsigned short* __restrict__ Ws1, unsigned short* __restrict__ Ws2,
    unsigned short* __restrict__ Ws3, int M, int nE)
{
    const int i  = blockIdx.x * 256 + threadIdx.x;
    const int nx = M * 16;
    if (i < nx) {
        const float4* xf = reinterpret_cast<const float4*>(x);
        float4 a = xf[2*i], b = xf[2*i + 1];
        uint4 o;
        o.x = (unsigned)f2bf(a.x) | ((unsigned)f2bf(a.y) << 16);
        o.y = (unsigned)f2bf(a.z) | ((unsigned)f2bf(a.w) << 16);
        o.z = (unsigned)f2bf(b.x) | ((unsigned)f2bf(b.y) << 16);
        o.w = (unsigned)f2bf(b.z) | ((unsigned)f2bf(b.w) << 16);
        const int node  = i >> 4;
        const int chunk = i & 15;
        const int cs    = chunk >> 2;
        const size_t idx = ((size_t)cs * M + node) * 32 + (chunk & 3) * 8;
        *reinterpret_cast<uint4*>(xb + idx) = o;
    } else if (i < nx + nE) {
        atomicAdd(&cnt[dst[i - nx]], 1);
    } else {
        int j = i - nx - nE;
        const float* W; unsigned short* D;
        if (j < 32768)       { W = W1; D = Ws1; }
        else if (j < 98304)  { W = W2; D = Ws2; j -= 32768; }
        else if (j < 163840) { W = W3; D = Ws3; j -= 98304; }
        else return;
        const int k = j >> 8, n = j & 255;
        D[((size_t)(k >> 3) * 256 + n) * 8 + (k & 7)] = f2bf(W[(size_t)k * 256 + n]);
    }
}

// ---------------- CSR scan (+ degree histogram, LDS-aggregated) -----------
__global__ __launch_bounds__(1024) void scan1_kernel(
    const int* __restrict__ cnt, int* __restrict__ excl,
    int* __restrict__ bsum, int* __restrict__ dhist, int n)
{
    __shared__ int sh[1024];
    __shared__ int lh[256];
    const int tid = threadIdx.x;
    if (tid < 256) lh[tid] = 0;
    const int i = blockIdx.x * 1024 + tid;
    int v = (i < n) ? cnt[i] : 0;
    sh[tid] = v;
    __syncthreads();
    if (i < n) atomicAdd(&lh[v > 255 ? 255 : v], 1);
    #pragma unroll
    for (int off = 1; off < 1024; off <<= 1) {
        int t = (tid >= off) ? sh[tid - off] : 0;
        __syncthreads();
        sh[tid] += t;
        __syncthreads();
    }
    if (i < n) excl[i] = sh[tid] - v;
    if (tid == 1023) bsum[blockIdx.x] = sh[1023];
    __syncthreads();
    if (tid < 256 && lh[tid]) atomicAdd(&dhist[tid], lh[tid]);
}

// 1-block exclusive scan of degree histogram -> dcur
__global__ __launch_bounds__(256) void dscan_kernel(
    const int* __restrict__ dhist, int* __restrict__ dcur)
{
    __shared__ int sh[256];
    const int t = threadIdx.x;
    int v = dhist[t];
    sh[t] = v;
    __syncthreads();
    #pragma unroll
    for (int off = 1; off < 256; off <<= 1) {
        int u = (t >= off) ? sh[t - off] : 0;
        __syncthreads();
        sh[t] += u;
        __syncthreads();
    }
    dcur[t] = sh[t] - v;   // exclusive
}

// scan3: finalize row_start, bucket cursors; counting-sort perm via
// per-block LDS hist + rank + one global atomic per (block,bin).
__global__ __launch_bounds__(1024) void scan3_kernel(
    const int* __restrict__ excl, const int* __restrict__ bsum,
    const int* __restrict__ cnt, int* __restrict__ dcur,
    int* __restrict__ perm,
    int* __restrict__ row_start, int* __restrict__ gcur,
    int n, int nE, int nbl)
{
    __shared__ int sb[64];
    __shared__ int lh[256];
    __shared__ int lb[256];
    const int tid = threadIdx.x;
    if (tid < 64) sb[tid] = (tid < nbl) ? bsum[tid] : 0;
    if (tid < 256) lh[tid] = 0;
    __syncthreads();
    #pragma unroll
    for (int off = 1; off < 64; off <<= 1) {
        int v = 0;
        if (tid < 64 && tid >= off) v = sb[tid - off];
        __syncthreads();
        if (tid < 64) sb[tid] += v;
        __syncthreads();
    }
    const int boff = sb[blockIdx.x] - bsum[blockIdx.x];
    const int i = blockIdx.x * 1024 + tid;
    int d = -1, r = 0;
    if (i < n) {
        int v = excl[i] + boff;
        row_start[i] = v;
        if ((i % BNODES) == 0) gcur[i / BNODES] = v;
        d = cnt[i]; if (d > 255) d = 255;
        r = atomicAdd(&lh[d], 1);           // LDS rank
    }
    __syncthreads();
    if (tid < 256) lb[tid] = lh[tid] ? atomicAdd(&dcur[tid], lh[tid]) : 0;
    __syncthreads();
    if (i < n) perm[lb[d] + r] = i;
    if (i == 0) row_start[n] = nE;
}

// ---------------- binned CSR scatter ----------------

__global__ __launch_bounds__(256) void binA_kernel(
    const int* __restrict__ src, const int* __restrict__ dst,
    int* __restrict__ gcur, unsigned* __restrict__ pair_buf, int nE)
{
    __shared__ int lhist[NBUK];
    __shared__ int lbase[NBUK];
    const int t = threadIdx.x;
    lhist[t] = 0;
    __syncthreads();

    const int e0 = blockIdx.x * 4096;
    int d[16], s[16], r[16];
    #pragma unroll
    for (int i = 0; i < 16; ++i) {
        const int e = e0 + i * 256 + t;
        if (e < nE) {
            d[i] = dst[e];
            s[i] = src[e];
            r[i] = atomicAdd(&lhist[d[i] / BNODES], 1);
        }
    }
    __syncthreads();
    lbase[t] = lhist[t] ? atomicAdd(&gcur[t], lhist[t]) : 0;
    __syncthreads();
    #pragma unroll
    for (int i = 0; i < 16; ++i) {
        const int e = e0 + i * 256 + t;
        if (e < nE)
            pair_buf[lbase[d[i] / BNODES] + r[i]] =
                ((unsigned)d[i] << 16) | (unsigned)s[i];
    }
}

__global__ __launch_bounds__(256) void binB_kernel(
    const unsigned* __restrict__ pair_buf, const int* __restrict__ row_start,
    unsigned short* __restrict__ adj, int M)
{
    __shared__ int lcur[BNODES];
    const int b   = blockIdx.x;
    const int nb0 = b * BNODES;
    const int nb1 = min(nb0 + BNODES, M);
    const int nn  = nb1 - nb0;
    const int t   = threadIdx.x;
    if (nn <= 0) return;
    for (int i = t; i < nn; i += 256) lcur[i] = row_start[nb0 + i];
    __syncthreads();
    const int p0 = row_start[nb0];
    const int p1 = row_start[nb1];
    for (int p = p0 + t; p < p1; p += 256) {
        const unsigned pr = pair_buf[p];
        const int dn = (int)(pr >> 16);
        const int pos = atomicAdd(&lcur[dn - nb0], 1);
        adj[pos] = (unsigned short)(pr & 0xFFFFu);
    }
}

// ---------------- sliced aggregation, degree-sorted ----------------

template <int CIN, int NSLICE>
__global__ __launch_bounds__(256) void agg_sliced(
    const unsigned short* __restrict__ Xcs,
    const int* __restrict__ row_start, const unsigned short* __restrict__ adj,
    const int* __restrict__ perm,
    const float* __restrict__ eps_arr, int layer,
    unsigned short* __restrict__ H, int M)
{
    constexpr int SHIFT = (NSLICE == 8) ? 3 : 2;

    const int cs   = blockIdx.x & (NSLICE - 1);
    const int grp  = blockIdx.x >> SHIFT;
    const int nidx = grp * 64 + (threadIdx.x >> 2);
    const int c8   = threadIdx.x & 3;
    if (nidx >= M) return;
    const int node = perm[nidx];

    const uint4* __restrict__ X4 =
        reinterpret_cast<const uint4*>(Xcs) + (size_t)cs * M * 4;

    float acc[8] = {};
    const int s0 = row_start[node];
    const int s1 = row_start[node + 1];
    const int deg = s1 - s0;

    int j = s0;
    if (deg >= 4) {
        const int jend = s0 + (deg & ~3);
        int a0 = adj[j], a1 = adj[j+1], a2 = adj[j+2], a3 = adj[j+3];
        uint4 p0 = X4[(size_t)a0 * 4 + c8];
        uint4 p1 = X4[(size_t)a1 * 4 + c8];
        uint4 p2 = X4[(size_t)a2 * 4 + c8];
        uint4 p3 = X4[(size_t)a3 * 4 + c8];
        for (j += 4; j < jend; j += 4) {
            const int b0 = adj[j], b1 = adj[j+1], b2 = adj[j+2], b3 = adj[j+3];
            const uint4 n0 = X4[(size_t)b0 * 4 + c8];
            const uint4 n1 = X4[(size_t)b1 * 4 + c8];
            const uint4 n2 = X4[(size_t)b2 * 4 + c8];
            const uint4 n3 = X4[(size_t)b3 * 4 + c8];
            ACC8(p0); ACC8(p1); ACC8(p2); ACC8(p3);
            p0 = n0; p1 = n1; p2 = n2; p3 = n3;
        }
        ACC8(p0); ACC8(p1); ACC8(p2); ACC8(p3);
    }
    for (; j < s1; ++j) {
        const uint4 v = X4[(size_t)adj[j] * 4 + c8];
        ACC8(v);
    }

    const uint4 xv = X4[(size_t)node * 4 + c8];
    const float epsv = 1.0f + eps_arr[layer];
    float o[8];
    o[0] = epsv * bflo(xv.x) + acc[0]; o[1] = epsv * bfhi(xv.x) + acc[1];
    o[2] = epsv * bflo(xv.y) + acc[2]; o[3] = epsv * bfhi(xv.y) + acc[3];
    o[4] = epsv * bflo(xv.z) + acc[4]; o[5] = epsv * bfhi(xv.z) + acc[5];
    o[6] = epsv * bflo(xv.w) + acc[6]; o[7] = epsv * bfhi(xv.w) + acc[7];

    uint4 ov;
    ov.x = (unsigned)f2bf(o[0]) | ((unsigned)f2bf(o[1]) << 16);
    ov.y = (unsigned)f2bf(o[2]) | ((unsigned)f2bf(o[3]) << 16);
    ov.z = (unsigned)f2bf(o[4]) | ((unsigned)f2bf(o[5]) << 16);
    ov.w = (unsigned)f2bf(o[6]) | ((unsigned)f2bf(o[7]) << 16);
    *reinterpret_cast<uint4*>(H + (size_t)node * CIN + cs * 32 + c8 * 8) = ov;
}

// ---------------- GEMM (unchanged) ----------------
template <int CIN, int RELU, int OUTMODE>
__global__ __launch_bounds__(256) void gemm_tiled(
    const unsigned short* __restrict__ H, const unsigned short* __restrict__ Wsub,
    const float* __restrict__ bias, void* __restrict__ out, int M)
{
    constexpr int S = CIN / 32;

    __shared__ __align__(16) unsigned short As[2][4][64][8];

    const int t    = threadIdx.x;
    const int bm   = blockIdx.x * 64;
    const int w    = t >> 6, lane = t & 63;
    const int lr   = lane & 15, ko = lane >> 4;

    const int srow = t & 63;
    const int skb  = t >> 6;
    const unsigned short* aG = H + (size_t)(bm + srow) * CIN + skb * 8;

    f32x4 acc[4][4];
    #pragma unroll
    for (int fn = 0; fn < 4; ++fn) {
        const float bb = bias[w*64 + fn*16 + lr];
        #pragma unroll
        for (int fm = 0; fm < 4; ++fm) {
            acc[fm][fn][0] = bb; acc[fm][fn][1] = bb;
            acc[fm][fn][2] = bb; acc[fm][fn][3] = bb;
        }
    }

    gload_lds16(aG, &As[0][skb][srow][0]);

    int cur = 0;
    for (int s = 0; s < S; ++s) {
        __syncthreads();
        if (s + 1 < S)
            gload_lds16(aG + (s+1)*32, &As[cur ^ 1][skb][srow][0]);

        short8 af[4], bf8[4];
        #pragma unroll
        for (int fm = 0; fm < 4; ++fm)
            af[fm] = *reinterpret_cast<const short8*>(&As[cur][ko][fm*16 + lr][0]);
        #pragma unroll
        for (int fn = 0; fn < 4; ++fn)
            bf8[fn] = *reinterpret_cast<const short8*>(
                Wsub + ((size_t)(s*4 + ko) * 256 + w*64 + fn*16 + lr) * 8);
        #pragma unroll
        for (int fm = 0; fm < 4; ++fm)
            #pragma unroll
            for (int fn = 0; fn < 4; ++fn)
                acc[fm][fn] = __builtin_amdgcn_mfma_f32_16x16x32_bf16(
                    af[fm], bf8[fn], acc[fm][fn], 0, 0, 0);

        cur ^= 1;
    }

    #pragma unroll
    for (int fm = 0; fm < 4; ++fm) {
        #pragma unroll
        for (int fn = 0; fn < 4; ++fn) {
            const int col = w*64 + fn*16 + lr;
            #pragma unroll
            for (int r = 0; r < 4; ++r) {
                const int row = bm + fm*16 + ko*4 + r;
                if (row < M) {
                    float v = acc[fm][fn][r];
                    if (RELU) v = fmaxf(v, 0.f);
                    if (OUTMODE == 1) {
                        ((unsigned short*)out)[(size_t)(col >> 5) * M * 32
                                               + (size_t)row * 32 + (col & 31)] = f2bf(v);
                    } else {
                        ((float*)out)[(size_t)row * 256 + col] = v;
                    }
                }
            }
        }
    }
}

// ---------------- launch ----------------

extern "C" void kernel_launch(void* const* d_in, const int* in_sizes, int n_in,
                              void* d_out, int out_size, void* d_ws, size_t ws_size,
                              hipStream_t stream)
{
    const float* x   = (const float*)d_in[0];
    const int*   ei  = (const int*)  d_in[1];
    const float* W1  = (const float*)d_in[2];
    const float* b1  = (const float*)d_in[3];
    const float* W2  = (const float*)d_in[4];
    const float* b2  = (const float*)d_in[5];
    const float* W3  = (const float*)d_in[6];
    const float* b3  = (const float*)d_in[7];
    const float* eps = (const float*)d_in[8];

    const int M  = in_sizes[0] / 128;   // 50000
    const int nE = in_sizes[1] / 2;     // 800000
    const int Mp = ((M + 63) / 64) * 64;
    const int* srcI = ei;
    const int* dstI = ei + nE;

    // workspace layout
    char* p = (char*)d_ws;
    unsigned short* xb_cs = (unsigned short*)p; p += (size_t)M  * 128 * 2;
    unsigned short* Arow  = (unsigned short*)p; p += (size_t)Mp * 256 * 2;
    unsigned short* s_cs  = (unsigned short*)p; p += (size_t)M  * 256 * 2;
    unsigned short* Ws1   = (unsigned short*)p; p += (size_t)128 * 256 * 2;
    unsigned short* Ws2   = (unsigned short*)p; p += (size_t)256 * 256 * 2;
    unsigned short* Ws3   = (unsigned short*)p; p += (size_t)256 * 256 * 2;
    int* cnt       = (int*)p; p += (size_t)M * 4;
    int* dhist     = (int*)p; p += 256 * 4;       // memset with cnt
    int* dcur      = (int*)p; p += 256 * 4;
    int* perm      = (int*)p; p += (size_t)M * 4;
    int* excl      = (int*)p; p += (size_t)M * 4;
    int* bsum      = (int*)p; p += 64 * 4;
    int* gcur      = (int*)p; p += NBUK * 4;
    int* row_start = (int*)p; p += (size_t)(M + 2) * 4;
    unsigned* pair_buf = (unsigned*)p; p += (size_t)nE * 4;
    unsigned short* adj = (unsigned short*)p; p += (size_t)nE * 2;

    const int nbl = (M + 1023) / 1024;   // 49

    hipMemsetAsync(cnt, 0, ((size_t)M + 256) * sizeof(int), stream);   // cnt + dhist
    {
        const int total = M * 16 + nE + 163840;
        prep_kernel<<<(total + 255) / 256, 256, 0, stream>>>(
            x, dstI, W1, W2, W3, xb_cs, cnt, Ws1, Ws2, Ws3, M, nE);
    }
    scan1_kernel<<<nbl, 1024, 0, stream>>>(cnt, excl, bsum, dhist, M);
    dscan_kernel<<<1, 256, 0, stream>>>(dhist, dcur);
    scan3_kernel<<<nbl, 1024, 0, stream>>>(excl, bsum, cnt, dcur, perm,
                                           row_start, gcur, M, nE, nbl);
    binA_kernel<<<(nE + 4095) / 4096, 256, 0, stream>>>(srcI, dstI, gcur, pair_buf, nE);
    binB_kernel<<<NBUK, 256, 0, stream>>>(pair_buf, row_start, adj, M);

    const int ablk1 = 4 * ((M + 63) / 64);
    const int ablk2 = 8 * ((M + 63) / 64);
    const int gblk  = Mp / 64;

    // layer 1 (CIN=128)
    agg_sliced<128, 4><<<ablk1, 256, 0, stream>>>(xb_cs, row_start, adj, perm, eps, 0, Arow, M);
    gemm_tiled<128, 1, 1><<<gblk, 256, 0, stream>>>(Arow, Ws1, b1, s_cs, M);

    // layer 2 (CIN=256)
    agg_sliced<256, 8><<<ablk2, 256, 0, stream>>>(s_cs, row_start, adj, perm, eps, 1, Arow, M);
    gemm_tiled<256, 1, 1><<<gblk, 256, 0, stream>>>(Arow, Ws2, b2, s_cs, M);

    // layer 3 (CIN=256)
    agg_sliced<256, 8><<<ablk2, 256, 0, stream>>>(s_cs, row_start, adj, perm, eps, 2, Arow, M);
    gemm_tiled<256, 0, 0><<<gblk, 256, 0, stream>>>(Arow, Ws3, b3, d_out, M);
}

// Round 20
// 249.447 us; speedup vs baseline: 1.9657x; 1.1083x over previous
//
#include <hip/hip_runtime.h>

// ---------------------------------------------------------------------------
// GIN 3-layer forward (R20 = exact R17 revert, the measured best @ 249.7us):
//   - degree-sort (R18/R19) REMOVED: counters showed locality loss (FETCH
//     36->99MB) exceeds straggler win. Natural node order restored.
//   prep:  x -> sliced bf16 [4][M][32], hist(dst), W -> k-subtiled bf16
//   CSR:   scan1 -> scan3 -> binned scatter (binA/binB, u16 adj)
//   agg:   XCD channel-sliced gather, prefetch rotation, natural order
//   gemm:  BM=64 dbuf gload_lds, B-frags from L2-resident Wsub
// ---------------------------------------------------------------------------

typedef __attribute__((ext_vector_type(8))) short short8;
typedef __attribute__((ext_vector_type(4))) float f32x4;

#define NBUK   256
#define BNODES 196   // ceil(50000/256)

__device__ inline unsigned short f2bf(float f) {
    union { float f; unsigned u; } v; v.f = f;
    unsigned r = v.u + 0x7fffu + ((v.u >> 16) & 1u);   // RNE
    return (unsigned short)(r >> 16);
}
__device__ inline float bflo(unsigned u) { return __uint_as_float(u << 16); }
__device__ inline float bfhi(unsigned u) { return __uint_as_float(u & 0xffff0000u); }

__device__ __forceinline__ void gload_lds16(const unsigned short* g, unsigned short* l) {
    __builtin_amdgcn_global_load_lds(
        (const __attribute__((address_space(1))) unsigned int*)g,
        (__attribute__((address_space(3))) unsigned int*)l,
        16, 0, 0);
}

#define ACC8(v) { acc[0]+=bflo(v.x); acc[1]+=bfhi(v.x); acc[2]+=bflo(v.y); acc[3]+=bfhi(v.y); \
                  acc[4]+=bflo(v.z); acc[5]+=bfhi(v.z); acc[6]+=bflo(v.w); acc[7]+=bfhi(v.w); }

// ---------------- prep: x -> sliced bf16 [4][M][32], hist, W subtiled ------
__global__ __launch_bounds__(256) void prep_kernel(
    const float* __restrict__ x, const int* __restrict__ dst,
    const float* __restrict__ W1, const float* __restrict__ W2,
    const float* __restrict__ W3,
    unsigned short* __restrict__ xb, int* __restrict__ cnt,
    unsigned short* __restrict__ Ws1, unsigned short* __restrict__ Ws2,
    unsigned short* __restrict__ Ws3, int M, int nE)
{
    const int i  = blockIdx.x * 256 + threadIdx.x;
    const int nx = M * 16;
    if (i < nx) {
        const float4* xf = reinterpret_cast<const float4*>(x);
        float4 a = xf[2*i], b = xf[2*i + 1];
        uint4 o;
        o.x = (unsigned)f2bf(a.x) | ((unsigned)f2bf(a.y) << 16);
        o.y = (unsigned)f2bf(a.z) | ((unsigned)f2bf(a.w) << 16);
        o.z = (unsigned)f2bf(b.x) | ((unsigned)f2bf(b.y) << 16);
        o.w = (unsigned)f2bf(b.z) | ((unsigned)f2bf(b.w) << 16);
        const int node  = i >> 4;
        const int chunk = i & 15;            // 8-ch chunk
        const int cs    = chunk >> 2;        // 32-ch slice 0..3
        const size_t idx = ((size_t)cs * M + node) * 32 + (chunk & 3) * 8;
        *reinterpret_cast<uint4*>(xb + idx) = o;
    } else if (i < nx + nE) {
        atomicAdd(&cnt[dst[i - nx]], 1);
    } else {
        int j = i - nx - nE;
        const float* W; unsigned short* D;
        if (j < 32768)       { W = W1; D = Ws1; }
        else if (j < 98304)  { W = W2; D = Ws2; j -= 32768; }
        else if (j < 163840) { W = W3; D = Ws3; j -= 98304; }
        else return;
        const int k = j >> 8, n = j & 255;
        D[((size_t)(k >> 3) * 256 + n) * 8 + (k & 7)] = f2bf(W[(size_t)k * 256 + n]);
    }
}

// ---------------- CSR scan ----------------

__global__ __launch_bounds__(1024) void scan1_kernel(
    const int* __restrict__ cnt, int* __restrict__ excl,
    int* __restrict__ bsum, int n)
{
    __shared__ int sh[1024];
    const int tid = threadIdx.x;
    const int i = blockIdx.x * 1024 + tid;
    int v = (i < n) ? cnt[i] : 0;
    sh[tid] = v;
    __syncthreads();
    #pragma unroll
    for (int off = 1; off < 1024; off <<= 1) {
        int t = (tid >= off) ? sh[tid - off] : 0;
        __syncthreads();
        sh[tid] += t;
        __syncthreads();
    }
    if (i < n) excl[i] = sh[tid] - v;
    if (tid == 1023) bsum[blockIdx.x] = sh[1023];
}

__global__ __launch_bounds__(1024) void scan3_kernel(
    const int* __restrict__ excl, const int* __restrict__ bsum,
    int* __restrict__ row_start, int* __restrict__ gcur,
    int n, int nE, int nbl)
{
    __shared__ int sb[64];
    const int tid = threadIdx.x;
    if (tid < 64) sb[tid] = (tid < nbl) ? bsum[tid] : 0;
    __syncthreads();
    #pragma unroll
    for (int off = 1; off < 64; off <<= 1) {
        int v = 0;
        if (tid < 64 && tid >= off) v = sb[tid - off];
        __syncthreads();
        if (tid < 64) sb[tid] += v;
        __syncthreads();
    }
    const int boff = sb[blockIdx.x] - bsum[blockIdx.x];
    const int i = blockIdx.x * 1024 + tid;
    if (i < n) {
        int v = excl[i] + boff;
        row_start[i] = v;
        if ((i % BNODES) == 0) gcur[i / BNODES] = v;
    }
    if (i == 0) row_start[n] = nE;
}

// ---------------- binned CSR scatter ----------------

__global__ __launch_bounds__(256) void binA_kernel(
    const int* __restrict__ src, const int* __restrict__ dst,
    int* __restrict__ gcur, unsigned* __restrict__ pair_buf, int nE)
{
    __shared__ int lhist[NBUK];
    __shared__ int lbase[NBUK];
    const int t = threadIdx.x;
    lhist[t] = 0;
    __syncthreads();

    const int e0 = blockIdx.x * 4096;
    int d[16], s[16], r[16];
    #pragma unroll
    for (int i = 0; i < 16; ++i) {
        const int e = e0 + i * 256 + t;
        if (e < nE) {
            d[i] = dst[e];
            s[i] = src[e];
            r[i] = atomicAdd(&lhist[d[i] / BNODES], 1);
        }
    }
    __syncthreads();
    lbase[t] = lhist[t] ? atomicAdd(&gcur[t], lhist[t]) : 0;
    __syncthreads();
    #pragma unroll
    for (int i = 0; i < 16; ++i) {
        const int e = e0 + i * 256 + t;
        if (e < nE)
            pair_buf[lbase[d[i] / BNODES] + r[i]] =
                ((unsigned)d[i] << 16) | (unsigned)s[i];
    }
}

__global__ __launch_bounds__(256) void binB_kernel(
    const unsigned* __restrict__ pair_buf, const int* __restrict__ row_start,
    unsigned short* __restrict__ adj, int M)
{
    __shared__ int lcur[BNODES];
    const int b   = blockIdx.x;
    const int nb0 = b * BNODES;
    const int nb1 = min(nb0 + BNODES, M);
    const int nn  = nb1 - nb0;
    const int t   = threadIdx.x;
    if (nn <= 0) return;
    for (int i = t; i < nn; i += 256) lcur[i] = row_start[nb0 + i];
    __syncthreads();
    const int p0 = row_start[nb0];
    const int p1 = row_start[nb1];
    for (int p = p0 + t; p < p1; p += 256) {
        const unsigned pr = pair_buf[p];
        const int dn = (int)(pr >> 16);
        const int pos = atomicAdd(&lcur[dn - nb0], 1);
        adj[pos] = (unsigned short)(pr & 0xFFFFu);
    }
}

// ---------------- sliced aggregation, prefetch rotation ----------------
// Xcs: [NSLICE][M][32] bf16. Thread owns one node's 16B sub-chunk
// (4 lanes/node, 64 nodes/block). slice = bid & (NSLICE-1) -> XCD-local L2.

template <int CIN, int NSLICE>
__global__ __launch_bounds__(256) void agg_sliced(
    const unsigned short* __restrict__ Xcs,
    const int* __restrict__ row_start, const unsigned short* __restrict__ adj,
    const float* __restrict__ eps_arr, int layer,
    unsigned short* __restrict__ H, int M)
{
    constexpr int SHIFT = (NSLICE == 8) ? 3 : 2;

    const int cs   = blockIdx.x & (NSLICE - 1);
    const int grp  = blockIdx.x >> SHIFT;
    const int node = grp * 64 + (threadIdx.x >> 2);
    const int c8   = threadIdx.x & 3;
    if (node >= M) return;

    const uint4* __restrict__ X4 =
        reinterpret_cast<const uint4*>(Xcs) + (size_t)cs * M * 4;

    float acc[8] = {};
    const int s0 = row_start[node];
    const int s1 = row_start[node + 1];
    const int deg = s1 - s0;

    int j = s0;
    if (deg >= 4) {
        const int jend = s0 + (deg & ~3);
        int a0 = adj[j], a1 = adj[j+1], a2 = adj[j+2], a3 = adj[j+3];
        uint4 p0 = X4[(size_t)a0 * 4 + c8];
        uint4 p1 = X4[(size_t)a1 * 4 + c8];
        uint4 p2 = X4[(size_t)a2 * 4 + c8];
        uint4 p3 = X4[(size_t)a3 * 4 + c8];
        for (j += 4; j < jend; j += 4) {
            const int b0 = adj[j], b1 = adj[j+1], b2 = adj[j+2], b3 = adj[j+3];
            const uint4 n0 = X4[(size_t)b0 * 4 + c8];
            const uint4 n1 = X4[(size_t)b1 * 4 + c8];
            const uint4 n2 = X4[(size_t)b2 * 4 + c8];
            const uint4 n3 = X4[(size_t)b3 * 4 + c8];
            ACC8(p0); ACC8(p1); ACC8(p2); ACC8(p3);
            p0 = n0; p1 = n1; p2 = n2; p3 = n3;
        }
        ACC8(p0); ACC8(p1); ACC8(p2); ACC8(p3);
    }
    for (; j < s1; ++j) {
        const uint4 v = X4[(size_t)adj[j] * 4 + c8];
        ACC8(v);
    }

    const uint4 xv = X4[(size_t)node * 4 + c8];
    const float epsv = 1.0f + eps_arr[layer];
    float o[8];
    o[0] = epsv * bflo(xv.x) + acc[0]; o[1] = epsv * bfhi(xv.x) + acc[1];
    o[2] = epsv * bflo(xv.y) + acc[2]; o[3] = epsv * bfhi(xv.y) + acc[3];
    o[4] = epsv * bflo(xv.z) + acc[4]; o[5] = epsv * bfhi(xv.z) + acc[5];
    o[6] = epsv * bflo(xv.w) + acc[6]; o[7] = epsv * bfhi(xv.w) + acc[7];

    uint4 ov;
    ov.x = (unsigned)f2bf(o[0]) | ((unsigned)f2bf(o[1]) << 16);
    ov.y = (unsigned)f2bf(o[2]) | ((unsigned)f2bf(o[3]) << 16);
    ov.z = (unsigned)f2bf(o[4]) | ((unsigned)f2bf(o[5]) << 16);
    ov.w = (unsigned)f2bf(o[6]) | ((unsigned)f2bf(o[7]) << 16);
    *reinterpret_cast<uint4*>(H + (size_t)node * CIN + cs * 32 + c8 * 8) = ov;
}

// ---------------- GEMM: BM=64, dbuf gload_lds A staging, B from L2 ---------
// OUTMODE: 0 = fp32 row-major, 1 = bf16 sliced-32 [8][M][32].

template <int CIN, int RELU, int OUTMODE>
__global__ __launch_bounds__(256) void gemm_tiled(
    const unsigned short* __restrict__ H, const unsigned short* __restrict__ Wsub,
    const float* __restrict__ bias, void* __restrict__ out, int M)
{
    constexpr int S = CIN / 32;

    __shared__ __align__(16) unsigned short As[2][4][64][8];

    const int t    = threadIdx.x;
    const int bm   = blockIdx.x * 64;
    const int w    = t >> 6, lane = t & 63;
    const int lr   = lane & 15, ko = lane >> 4;

    const int srow = t & 63;
    const int skb  = t >> 6;
    const unsigned short* aG = H + (size_t)(bm + srow) * CIN + skb * 8;

    f32x4 acc[4][4];
    #pragma unroll
    for (int fn = 0; fn < 4; ++fn) {
        const float bb = bias[w*64 + fn*16 + lr];
        #pragma unroll
        for (int fm = 0; fm < 4; ++fm) {
            acc[fm][fn][0] = bb; acc[fm][fn][1] = bb;
            acc[fm][fn][2] = bb; acc[fm][fn][3] = bb;
        }
    }

    gload_lds16(aG, &As[0][skb][srow][0]);

    int cur = 0;
    for (int s = 0; s < S; ++s) {
        __syncthreads();
        if (s + 1 < S)
            gload_lds16(aG + (s+1)*32, &As[cur ^ 1][skb][srow][0]);

        short8 af[4], bf8[4];
        #pragma unroll
        for (int fm = 0; fm < 4; ++fm)
            af[fm] = *reinterpret_cast<const short8*>(&As[cur][ko][fm*16 + lr][0]);
        #pragma unroll
        for (int fn = 0; fn < 4; ++fn)
            bf8[fn] = *reinterpret_cast<const short8*>(
                Wsub + ((size_t)(s*4 + ko) * 256 + w*64 + fn*16 + lr) * 8);
        #pragma unroll
        for (int fm = 0; fm < 4; ++fm)
            #pragma unroll
            for (int fn = 0; fn < 4; ++fn)
                acc[fm][fn] = __builtin_amdgcn_mfma_f32_16x16x32_bf16(
                    af[fm], bf8[fn], acc[fm][fn], 0, 0, 0);

        cur ^= 1;
    }

    #pragma unroll
    for (int fm = 0; fm < 4; ++fm) {
        #pragma unroll
        for (int fn = 0; fn < 4; ++fn) {
            const int col = w*64 + fn*16 + lr;
            #pragma unroll
            for (int r = 0; r < 4; ++r) {
                const int row = bm + fm*16 + ko*4 + r;
                if (row < M) {
                    float v = acc[fm][fn][r];
                    if (RELU) v = fmaxf(v, 0.f);
                    if (OUTMODE == 1) {
                        ((unsigned short*)out)[(size_t)(col >> 5) * M * 32
                                               + (size_t)row * 32 + (col & 31)] = f2bf(v);
                    } else {
                        ((float*)out)[(size_t)row * 256 + col] = v;
                    }
                }
            }
        }
    }
}

// ---------------- launch ----------------

extern "C" void kernel_launch(void* const* d_in, const int* in_sizes, int n_in,
                              void* d_out, int out_size, void* d_ws, size_t ws_size,
                              hipStream_t stream)
{
    const float* x   = (const float*)d_in[0];
    const int*   ei  = (const int*)  d_in[1];
    const float* W1  = (const float*)d_in[2];
    const float* b1  = (const float*)d_in[3];
    const float* W2  = (const float*)d_in[4];
    const float* b2  = (const float*)d_in[5];
    const float* W3  = (const float*)d_in[6];
    const float* b3  = (const float*)d_in[7];
    const float* eps = (const float*)d_in[8];

    const int M  = in_sizes[0] / 128;   // 50000
    const int nE = in_sizes[1] / 2;     // 800000
    const int Mp = ((M + 63) / 64) * 64;
    const int* srcI = ei;
    const int* dstI = ei + nE;

    // workspace layout
    char* p = (char*)d_ws;
    unsigned short* xb_cs = (unsigned short*)p; p += (size_t)M  * 128 * 2;  // [4][M][32]
    unsigned short* Arow  = (unsigned short*)p; p += (size_t)Mp * 256 * 2;  // row-major A
    unsigned short* s_cs  = (unsigned short*)p; p += (size_t)M  * 256 * 2;  // [8][M][32]
    unsigned short* Ws1   = (unsigned short*)p; p += (size_t)128 * 256 * 2;
    unsigned short* Ws2   = (unsigned short*)p; p += (size_t)256 * 256 * 2;
    unsigned short* Ws3   = (unsigned short*)p; p += (size_t)256 * 256 * 2;
    int* cnt       = (int*)p; p += (size_t)M * 4;
    int* excl      = (int*)p; p += (size_t)M * 4;
    int* bsum      = (int*)p; p += 64 * 4;
    int* gcur      = (int*)p; p += NBUK * 4;
    int* row_start = (int*)p; p += (size_t)(M + 2) * 4;
    unsigned* pair_buf = (unsigned*)p; p += (size_t)nE * 4;
    unsigned short* adj = (unsigned short*)p; p += (size_t)nE * 2;

    const int nbl = (M + 1023) / 1024;   // 49

    hipMemsetAsync(cnt, 0, (size_t)M * sizeof(int), stream);
    {
        const int total = M * 16 + nE + 163840;
        prep_kernel<<<(total + 255) / 256, 256, 0, stream>>>(
            x, dstI, W1, W2, W3, xb_cs, cnt, Ws1, Ws2, Ws3, M, nE);
    }
    scan1_kernel<<<nbl, 1024, 0, stream>>>(cnt, excl, bsum, M);
    scan3_kernel<<<nbl, 1024, 0, stream>>>(excl, bsum, row_start, gcur, M, nE, nbl);
    binA_kernel<<<(nE + 4095) / 4096, 256, 0, stream>>>(srcI, dstI, gcur, pair_buf, nE);
    binB_kernel<<<NBUK, 256, 0, stream>>>(pair_buf, row_start, adj, M);

    const int ablk1 = 4 * ((M + 63) / 64);   // layer 1: 4 slices
    const int ablk2 = 8 * ((M + 63) / 64);   // layers 2/3: 8 slices
    const int gblk  = Mp / 64;               // 782

    // layer 1 (CIN=128): xb_cs -> Arow -> s_cs
    agg_sliced<128, 4><<<ablk1, 256, 0, stream>>>(xb_cs, row_start, adj, eps, 0, Arow, M);
    gemm_tiled<128, 1, 1><<<gblk, 256, 0, stream>>>(Arow, Ws1, b1, s_cs, M);

    // layer 2 (CIN=256): s_cs -> Arow -> s_cs
    agg_sliced<256, 8><<<ablk2, 256, 0, stream>>>(s_cs, row_start, adj, eps, 1, Arow, M);
    gemm_tiled<256, 1, 1><<<gblk, 256, 0, stream>>>(Arow, Ws2, b2, s_cs, M);

    // layer 3 (CIN=256): s_cs -> Arow -> d_out (fp32 row-major)
    agg_sliced<256, 8><<<ablk2, 256, 0, stream>>>(s_cs, row_start, adj, eps, 2, Arow, M);
    gemm_tiled<256, 0, 0><<<gblk, 256, 0, stream>>>(Arow, Ws3, b3, d_out, M);
}